// Round 9
// baseline (207.129 us; speedup 1.0000x reference)
//
#include <hip/hip_runtime.h>
#include <hip/hip_bf16.h>
#include <math.h>

#define BATCH 8
#define SEQ   2048
#define CH    256
#define NH    4
#define HD    64
#define NQB   (SEQ / 64)      // 32 query tiles of 64
// Q pre-scale: 64^-0.5 * log2(e)  (softmax runs in exp2 domain)
#define QSCALE 0.18033688011112042f

typedef short  bfrag __attribute__((ext_vector_type(8)));  // 8 bf16 (4 VGPRs)
typedef float  ffrag __attribute__((ext_vector_type(4)));  // 4 fp32 acc
typedef unsigned short ushort_t;

__device__ __forceinline__ unsigned short f2bf(float f) {
    union { float f; unsigned int u; } v; v.f = f;
    unsigned int r = v.u + 0x7FFF + ((v.u >> 16) & 1);   // RNE
    return (unsigned short)(r >> 16);
}
__device__ __forceinline__ unsigned int pack2(float a, float b) {
    const __hip_bfloat162 p = __float22bfloat162_rn(make_float2(a, b));
    return *(const unsigned int*)&p;
}

// ---------------------------------------------------------------------------
// Prep: x -> bf16 (vectorized), Wqkv/Wproj -> transposed bf16.
// ---------------------------------------------------------------------------
#define XN  (BATCH * SEQ * CH / 4)   // 1048576 float4 groups
#define WQN (CH * 3 * CH)            // 196608
#define WPN (CH * CH)                // 65536

__global__ __launch_bounds__(256) void prep_kernel(
    const float* __restrict__ x, const float* __restrict__ Wqkv,
    const float* __restrict__ Wproj,
    ushort_t* __restrict__ xb, ushort_t* __restrict__ WqkvT,
    ushort_t* __restrict__ WprojT) {
    const int fid = blockIdx.x * 256 + threadIdx.x;
    if (fid < XN) {
        const float4 v = ((const float4*)x)[fid];
        ushort4 p;
        p.x = f2bf(v.x); p.y = f2bf(v.y); p.z = f2bf(v.z); p.w = f2bf(v.w);
        ((ushort4*)xb)[fid] = p;
    } else if (fid < XN + WQN) {
        const int i = fid - XN;
        const int n = i >> 8, k = i & 255;
        WqkvT[n * CH + k] = f2bf(Wqkv[k * (3 * CH) + n]);
    } else if (fid < XN + WQN + WPN) {
        const int i = fid - XN - WQN;
        const int n = i >> 8, k = i & 255;
        WprojT[n * CH + k] = f2bf(Wproj[k * CH + n]);
    }
}

// ---------------------------------------------------------------------------
// QKV MFMA GEMM, LDS-free main loop: xb(16384x256 bf16) @ WqkvT^T + bqkv.
// Fragments loaded directly from global (L1/L2-resident operands; only 2x
// reuse per block made LDS staging pure overhead). 128x128 tile, 4 waves
// as 2x2 of 64x64. LDS used only for the transpose epilogue.
// Outputs: Q(*QSCALE),K as [BH,T,D] bf16; V^T as [BH,D,T] bf16.
// ---------------------------------------------------------------------------
__global__ __launch_bounds__(256) void qkv_mfma_kernel(
    const ushort_t* __restrict__ xb, const ushort_t* __restrict__ Wt,
    const float* __restrict__ bias,
    ushort_t* __restrict__ Qb, ushort_t* __restrict__ Kb,
    ushort_t* __restrict__ Vtb) {
    __shared__ ushort_t T[128][136];   // epilogue transpose buffer (34.8 KB)

    const int tid = threadIdx.x;
    const int wv  = tid >> 6;
    const int ln  = tid & 63;
    const int l15 = ln & 15;
    const int l4  = ln >> 4;
    const int wr  = wv >> 1;          // wave row 0..1
    const int wc  = wv & 1;           // wave col 0..1
    const int n0  = blockIdx.x * 128;
    const int m0  = blockIdx.y * 128;

    ffrag acc[4][4];
    #pragma unroll
    for (int i = 0; i < 4; i++)
        #pragma unroll
        for (int j = 0; j < 4; j++) acc[i][j] = (ffrag){0.f, 0.f, 0.f, 0.f};

    const ushort_t* Ap[4];
    const ushort_t* Bp[4];
    #pragma unroll
    for (int i = 0; i < 4; i++)
        Ap[i] = xb + (size_t)(m0 + wr * 64 + i * 16 + l15) * CH + l4 * 8;
    #pragma unroll
    for (int j = 0; j < 4; j++)
        Bp[j] = Wt + (size_t)(n0 + wc * 64 + j * 16 + l15) * CH + l4 * 8;

    #pragma unroll 2
    for (int kc = 0; kc < 8; kc++) {      // 8 chunks of K=32
        const int off = kc * 32;
        bfrag a[4], b[4];
        #pragma unroll
        for (int i = 0; i < 4; i++) a[i] = *(const bfrag*)(Ap[i] + off);
        #pragma unroll
        for (int j = 0; j < 4; j++) b[j] = *(const bfrag*)(Bp[j] + off);
        #pragma unroll
        for (int i = 0; i < 4; i++)
            #pragma unroll
            for (int j = 0; j < 4; j++)
                acc[i][j] = __builtin_amdgcn_mfma_f32_16x16x32_bf16(a[i], b[j], acc[i][j], 0, 0, 0);
    }

    const int mat = n0 >> 8;                 // block-uniform: 0=Q 1=K 2=V
    const int bb  = m0 >> 11;                // block-uniform
    const int t0  = m0 & (SEQ - 1);

    if (mat < 2) {
        // Q/K: transpose to T[t_local][n_local], then coalesced [T,D] stores.
        const float sc = (mat == 0) ? QSCALE : 1.0f;
        #pragma unroll
        for (int j = 0; j < 4; j++) {
            const int n_local = wc * 64 + j * 16 + l15;
            const float bj = bias[n0 + n_local];
            #pragma unroll
            for (int i = 0; i < 4; i++) {
                const int m_base = wr * 64 + i * 16 + l4 * 4;
                #pragma unroll
                for (int r = 0; r < 4; r++)
                    T[m_base + r][n_local] = f2bf((acc[i][j][r] + bj) * sc);
            }
        }
        __syncthreads();
        ushort_t* dst = (mat == 0) ? Qb : Kb;
        #pragma unroll
        for (int rr = 0; rr < 8; rr++) {
            const int fid = tid + rr * 256;
            const int row = fid >> 4;            // t_local 0..127
            const int c8  = (fid & 15) * 8;      // n_local chunk
            const int n_glob = n0 + c8;
            const int h = (n_glob >> 6) & 3;
            const int d = n_glob & 63;
            *(uint4*)&dst[((size_t)((bb * NH + h) * SEQ) + t0 + row) * HD + d] =
                *(const uint4*)&T[row][c8];
        }
    } else {
        // V: transpose to T[n_local][m_local], then coalesced [D,T] stores.
        #pragma unroll
        for (int j = 0; j < 4; j++) {
            const int n_local = wc * 64 + j * 16 + l15;
            const float bj = bias[n0 + n_local];
            #pragma unroll
            for (int i = 0; i < 4; i++) {
                const int m_base = wr * 64 + i * 16 + l4 * 4;
                ushort4 pk;
                pk.x = f2bf(acc[i][j][0] + bj);
                pk.y = f2bf(acc[i][j][1] + bj);
                pk.z = f2bf(acc[i][j][2] + bj);
                pk.w = f2bf(acc[i][j][3] + bj);
                *(ushort4*)&T[n_local][m_base] = pk;
            }
        }
        __syncthreads();
        #pragma unroll
        for (int rr = 0; rr < 8; rr++) {
            const int fid = tid + rr * 256;
            const int row = fid >> 4;            // n_local 0..127
            const int c8  = (fid & 15) * 8;      // m_local chunk
            const int n_glob = n0 + row;
            const int h = (n_glob >> 6) & 3;
            const int d = n_glob & 63;
            *(uint4*)&Vtb[(size_t)((bb * NH + h) * HD + d) * SEQ + t0 + c8] =
                *(const uint4*)&T[row][c8];
        }
    }
}

// ---------------------------------------------------------------------------
// MFMA flash attention (causal), S^T form, exp2 softmax.
// Round-9: K-fragments loaded DIRECTLY from global (XCD-pinned L2) -> K never
// touches LDS. LDS = V double-buffer (16 KB) + P (8 KB) = 24 KB.
// V: register prefetch one iter ahead, committed before the single barrier.
// ---------------------------------------------------------------------------
__global__ __launch_bounds__(256, 4) void attn_mfma_kernel(
    const ushort_t* __restrict__ Qb, const ushort_t* __restrict__ Kb,
    const ushort_t* __restrict__ Vtb, ushort_t* __restrict__ out) {
    __shared__ ushort_t Ps[64 * 64];       // P tiles (wave-private 16-row bands)
    __shared__ ushort_t VV[2 * 64 * 64];   // V0 | V1 (8 KB each)

    const int tid = threadIdx.x;
    const int wv  = tid >> 6;
    const int ln  = tid & 63;
    const int l15 = ln & 15;
    const int l4  = ln >> 4;
    const int e   = l15 & 7;

    const int L  = blockIdx.x;
    const int g  = L & 255;
    const int s4 = L >> 8;               // dispatch wave 0..3
    const int v  = g >> 5;               // 0..7
    // longest-first; per-CU slot set {31-v, 16+v, 15-v, v} sums to 66 iters
    const int qb = (s4 == 0) ? (31 - v) : (s4 == 1) ? (16 + v) : (s4 == 2) ? (15 - v) : v;
    const int bh = g & 31;
    const int b  = bh >> 2;
    const int h  = bh & 3;

    // ---- Q fragments straight from global (B-operand: B[n=q][k]) ----
    const ushort_t* Qp = Qb + ((size_t)(bh * SEQ + qb * 64 + wv * 16 + l15)) * HD + l4 * 8;
    const bfrag bq0 = *(const bfrag*)Qp;
    const bfrag bq1 = *(const bfrag*)(Qp + 32);

    // ---- staging geometry (V only) ----
    const ushort_t* Kbase = Kb  + (size_t)bh * SEQ * HD;
    const ushort_t* Vbase = Vtb + (size_t)bh * HD * SEQ;
    const int srow  = tid >> 3;            // 0..31
    const int sc    = tid & 7;             // logical 16B-chunk
    const int voffA = srow * SEQ + sc * 8;                   // V global
    const int soffA = srow * 64 + ((sc ^ (srow & 7)) * 8);   // swizzled LDS

    // ---- fragment read offsets ----
    const int kf0 = l15 * 64 + ((l4 ^ e) * 8);   // V-frag: + n*1024 ; ^32
    const int pf0 = (wv * 16 + l15) * 64 + ((l4 ^ e) * 8);
    const int pp  = e >> 1;
    const int pwb = (wv * 16 + l15) * 64 + (((l4 >> 1) ^ (e & 1)) * 8) + (l4 & 1) * 4;
    // K direct-global row base for this lane's A-operand rows
    const ushort_t* Kfrag = Kbase + (size_t)l15 * HD + l4 * 8;

    // ---- prologue: V tile 0 -> LDS buf0 ; V tile 1 -> regs ----
    uint4 kV0 = *(const uint4*)&Vbase[voffA];
    uint4 kV1 = *(const uint4*)&Vbase[voffA + 32 * SEQ];
    *(uint4*)&VV[soffA]        = kV0;
    *(uint4*)&VV[soffA + 2048] = kV1;
    if (qb >= 1) {
        kV0 = *(const uint4*)&Vbase[64 + voffA];
        kV1 = *(const uint4*)&Vbase[64 + voffA + 32 * SEQ];
    }

    ffrag o[4];
    #pragma unroll
    for (int n = 0; n < 4; n++) o[n] = (ffrag){0.f, 0.f, 0.f, 0.f};
    float m_q = -INFINITY;
    float l_q = 0.f;
    const int qg_l = qb * 64 + wv * 16 + l15;

    for (int kt = 0; kt <= qb; kt++) {
        if (kt > 0) {
            const int kb = (kt & 1) * 4096;
            *(uint4*)&VV[kb + soffA]        = kV0;
            *(uint4*)&VV[kb + soffA + 2048] = kV1;
            if (kt < qb) {   // issue V loads for tile kt+1 (land during compute)
                const ushort_t* Vtp = Vbase + (kt + 1) * 64;
                kV0 = *(const uint4*)&Vtp[voffA];
                kV1 = *(const uint4*)&Vtp[voffA + 32 * SEQ];
            }
        }
        __syncthreads();   // the ONLY barrier (protects V buffer)

        const ushort_t* Vbuf = VV + (kt & 1) * 4096;

        // ---- S^T = K Q^T ; K A-frags DIRECT from global (L2-pinned) ----
        const ushort_t* Kt = Kfrag + (size_t)kt * 64 * HD;
        ffrag s[4];
        #pragma unroll
        for (int n = 0; n < 4; n++) {
            const bfrag ak0 = *(const bfrag*)(Kt + n * 16 * HD);
            const bfrag ak1 = *(const bfrag*)(Kt + n * 16 * HD + 32);
            ffrag z = (ffrag){0.f, 0.f, 0.f, 0.f};
            z = __builtin_amdgcn_mfma_f32_16x16x32_bf16(ak0, bq0, z, 0, 0, 0);
            z = __builtin_amdgcn_mfma_f32_16x16x32_bf16(ak1, bq1, z, 0, 0, 0);
            s[n] = z;
        }
        if (kt == qb) {   // causal mask on the diagonal tile
            #pragma unroll
            for (int n = 0; n < 4; n++)
                #pragma unroll
                for (int r = 0; r < 4; r++)
                    if (kt * 64 + n * 16 + l4 * 4 + r > qg_l) s[n][r] = -INFINITY;
        }

        // ---- online softmax (exp2 domain) ----
        float mx = s[0][0];
        #pragma unroll
        for (int n = 0; n < 4; n++)
            #pragma unroll
            for (int r = 0; r < 4; r++) mx = fmaxf(mx, s[n][r]);
        mx = fmaxf(mx, __shfl_xor(mx, 16));
        mx = fmaxf(mx, __shfl_xor(mx, 32));
        const float mn = fmaxf(m_q, mx);
        const float alpha = __builtin_amdgcn_exp2f(m_q - mn);
        m_q = mn;

        float rs = 0.f;
        #pragma unroll
        for (int n = 0; n < 4; n++)
            #pragma unroll
            for (int r = 0; r < 4; r++) {
                const float p = __builtin_amdgcn_exp2f(s[n][r] - mn);
                s[n][r] = p;
                rs += p;
            }
        rs += __shfl_xor(rs, 16);
        rs += __shfl_xor(rs, 32);
        l_q = l_q * alpha + rs;

        // ---- pack P (bf16, A-layout, swizzled, wave-private rows) ----
        #pragma unroll
        for (int n = 0; n < 4; n++) {
            uint2 pk;
            pk.x = pack2(s[n][0], s[n][1]);
            pk.y = pack2(s[n][2], s[n][3]);
            *(uint2*)&Ps[pwb + ((n ^ pp) << 4)] = pk;
        }

        // ---- O *= alpha (row l4*4+r alpha via shuffle) ----
        #pragma unroll
        for (int r = 0; r < 4; r++) {
            const float ar = __shfl(alpha, l4 * 20 + r);
            #pragma unroll
            for (int n = 0; n < 4; n++) o[n][r] *= ar;
        }

        // ---- O += P @ V ----
        const bfrag ap0 = *(const bfrag*)&Ps[pf0];
        const bfrag ap1 = *(const bfrag*)&Ps[pf0 ^ 32];
        #pragma unroll
        for (int n = 0; n < 4; n++) {
            const bfrag bv0 = *(const bfrag*)&Vbuf[n * 1024 + kf0];
            const bfrag bv1 = *(const bfrag*)&Vbuf[n * 1024 + (kf0 ^ 32)];
            o[n] = __builtin_amdgcn_mfma_f32_16x16x32_bf16(ap0, bv0, o[n], 0, 0, 0);
            o[n] = __builtin_amdgcn_mfma_f32_16x16x32_bf16(ap1, bv1, o[n], 0, 0, 0);
        }
    }

    // ---- normalize + store O (bf16, [B,T,C]) ----
    const int tg = qb * 64 + wv * 16 + l4 * 4;
    ushort_t* op = out + (size_t)(b * SEQ) * CH + h * HD;
    #pragma unroll
    for (int r = 0; r < 4; r++) {
        const float lr = __shfl(l_q, l4 * 20 + r);
        const float li = 1.0f / lr;
        #pragma unroll
        for (int n = 0; n < 4; n++)
            op[(size_t)(tg + r) * CH + n * 16 + l15] = f2bf(o[n][r] * li);
    }
}

// ---------------------------------------------------------------------------
// Proj MFMA GEMM, fully LDS-free & barrier-free: attn_b @ WprojT^T + bproj.
// 64x64 tile, 4 waves as 2x2 of 32x32; fragments direct from global.
// ---------------------------------------------------------------------------
__global__ __launch_bounds__(256) void proj_mfma_kernel(
    const ushort_t* __restrict__ Ab, const ushort_t* __restrict__ Wt,
    const float* __restrict__ bias, float* __restrict__ O) {
    const int tid = threadIdx.x;
    const int wv  = tid >> 6;
    const int ln  = tid & 63;
    const int l15 = ln & 15;
    const int l4  = ln >> 4;
    const int wr  = wv >> 1;          // 0..1 -> 32-row band
    const int wc  = wv & 1;           // 0..1 -> 32-col band
    const int n0  = blockIdx.x * 64;
    const int m0  = blockIdx.y * 64;

    ffrag acc[2][2];
    #pragma unroll
    for (int i = 0; i < 2; i++)
        #pragma unroll
        for (int j = 0; j < 2; j++) acc[i][j] = (ffrag){0.f, 0.f, 0.f, 0.f};

    const ushort_t* Ap[2];
    const ushort_t* Bp[2];
    #pragma unroll
    for (int i = 0; i < 2; i++)
        Ap[i] = Ab + (size_t)(m0 + wr * 32 + i * 16 + l15) * CH + l4 * 8;
    #pragma unroll
    for (int j = 0; j < 2; j++)
        Bp[j] = Wt + (size_t)(n0 + wc * 32 + j * 16 + l15) * CH + l4 * 8;

    #pragma unroll 4
    for (int kc = 0; kc < 8; kc++) {
        const int off = kc * 32;
        bfrag a[2], b[2];
        #pragma unroll
        for (int i = 0; i < 2; i++) a[i] = *(const bfrag*)(Ap[i] + off);
        #pragma unroll
        for (int j = 0; j < 2; j++) b[j] = *(const bfrag*)(Bp[j] + off);
        #pragma unroll
        for (int i = 0; i < 2; i++)
            #pragma unroll
            for (int j = 0; j < 2; j++)
                acc[i][j] = __builtin_amdgcn_mfma_f32_16x16x32_bf16(a[i], b[j], acc[i][j], 0, 0, 0);
    }

    #pragma unroll
    for (int j = 0; j < 2; j++) {
        const int n = n0 + wc * 32 + j * 16 + l15;
        const float bj = bias[n];
        #pragma unroll
        for (int i = 0; i < 2; i++) {
            const int m = m0 + wr * 32 + i * 16 + l4 * 4;
            #pragma unroll
            for (int r = 0; r < 4; r++)
                O[(size_t)(m + r) * CH + n] = acc[i][j][r] + bj;
        }
    }
}

extern "C" void kernel_launch(void* const* d_in, const int* in_sizes, int n_in,
                              void* d_out, int out_size, void* d_ws, size_t ws_size,
                              hipStream_t stream) {
    const float* x     = (const float*)d_in[0];
    const float* Wqkv  = (const float*)d_in[1];
    const float* bqkv  = (const float*)d_in[2];
    const float* Wproj = (const float*)d_in[3];
    const float* bproj = (const float*)d_in[4];
    float* out = (float*)d_out;

    const size_t BHTD = (size_t)BATCH * NH * SEQ * HD;   // 4,194,304
    ushort_t* xb     = (ushort_t*)d_ws;
    ushort_t* WqkvT  = xb + BHTD;
    ushort_t* WprojT = WqkvT + (size_t)3 * CH * CH;
    ushort_t* Qb     = WprojT + (size_t)CH * CH;
    ushort_t* Kb     = Qb + BHTD;
    ushort_t* Vtb    = Kb + BHTD;
    ushort_t* attn_b = Vtb + BHTD;

    const int M = BATCH * SEQ;   // 16384

    {
        const int total = XN + WQN + WPN;
        prep_kernel<<<(total + 255) / 256, 256, 0, stream>>>(x, Wqkv, Wproj, xb, WqkvT, WprojT);
    }
    {
        dim3 grid((3 * CH) / 128, M / 128);
        qkv_mfma_kernel<<<grid, 256, 0, stream>>>(xb, WqkvT, bqkv, Qb, Kb, Vtb);
    }
    {
        attn_mfma_kernel<<<dim3(NQB * BATCH * NH), 256, 0, stream>>>(Qb, Kb, Vtb, attn_b);
    }
    {
        dim3 grid(CH / 64, M / 64);
        proj_mfma_kernel<<<grid, 256, 0, stream>>>(attn_b, WprojT, bproj, out);
    }
}

// Round 10
// 152.407 us; speedup vs baseline: 1.3591x; 1.3591x over previous
//
#include <hip/hip_runtime.h>
#include <hip/hip_bf16.h>
#include <math.h>

#define BATCH 8
#define SEQ   2048
#define CH    256
#define NH    4
#define HD    64
#define NQB   (SEQ / 64)      // 32 query tiles of 64
// Q pre-scale: 64^-0.5 * log2(e)  (softmax runs in exp2 domain)
#define QSCALE 0.18033688011112042f

typedef short  bfrag __attribute__((ext_vector_type(8)));  // 8 bf16 (4 VGPRs)
typedef float  ffrag __attribute__((ext_vector_type(4)));  // 4 fp32 acc
typedef unsigned short ushort_t;

__device__ __forceinline__ unsigned short f2bf(float f) {
    union { float f; unsigned int u; } v; v.f = f;
    unsigned int r = v.u + 0x7FFF + ((v.u >> 16) & 1);   // RNE
    return (unsigned short)(r >> 16);
}
__device__ __forceinline__ unsigned int pack2(float a, float b) {
    const __hip_bfloat162 p = __float22bfloat162_rn(make_float2(a, b));
    return *(const unsigned int*)&p;
}
// async 16B global -> LDS DMA (dest = wave-uniform base + lane*16)
__device__ __forceinline__ void dma16(const ushort_t* g, ushort_t* l) {
    __builtin_amdgcn_global_load_lds(
        (const __attribute__((address_space(1))) unsigned int*)g,
        (__attribute__((address_space(3))) unsigned int*)l, 16, 0, 0);
}

// ---------------------------------------------------------------------------
// Prep: x -> bf16 (vectorized), Wqkv/Wproj -> transposed bf16 (W^T[n][k]).
// ---------------------------------------------------------------------------
#define XN  (BATCH * SEQ * CH / 4)   // 1048576 float4 groups
#define WQN (CH * 3 * CH)            // 196608
#define WPN (CH * CH)                // 65536

__global__ __launch_bounds__(256) void prep_kernel(
    const float* __restrict__ x, const float* __restrict__ Wqkv,
    const float* __restrict__ Wproj,
    ushort_t* __restrict__ xb, ushort_t* __restrict__ WqkvT,
    ushort_t* __restrict__ WprojT) {
    const int fid = blockIdx.x * 256 + threadIdx.x;
    if (fid < XN) {
        const float4 v = ((const float4*)x)[fid];
        ushort4 p;
        p.x = f2bf(v.x); p.y = f2bf(v.y); p.z = f2bf(v.z); p.w = f2bf(v.w);
        ((ushort4*)xb)[fid] = p;
    } else if (fid < XN + WQN) {
        const int i = fid - XN;
        const int n = i >> 8, k = i & 255;
        WqkvT[n * CH + k] = f2bf(Wqkv[k * (3 * CH) + n]);
    } else if (fid < XN + WQN + WPN) {
        const int i = fid - XN - WQN;
        const int n = i >> 8, k = i & 255;
        WprojT[n * CH + k] = f2bf(Wproj[k * CH + n]);
    }
}

// ---------------------------------------------------------------------------
// QKV MFMA GEMM: xb(16384x256 bf16) @ WqkvT^T + bqkv.
// 128x128 tile, 4 waves (2x2 of 64x64), BK=64, single-buffered LDS staged via
// global_load_lds width=16 (m97 pattern), source-side XOR swizzle, unpadded
// rows. Outputs: Q(*QSCALE),K as [BH,T,D]; V^T as [BH,D,T].
// ---------------------------------------------------------------------------
__global__ __launch_bounds__(256) void qkv_mfma_kernel(
    const ushort_t* __restrict__ xb, const ushort_t* __restrict__ Wt,
    const float* __restrict__ bias,
    ushort_t* __restrict__ Qb, ushort_t* __restrict__ Kb,
    ushort_t* __restrict__ Vtb) {
    __shared__ ushort_t smem[17408];   // A(8K) | B(8K) staging; T[128][136] epi
    ushort_t* As = smem;
    ushort_t* Bs = smem + 8192;

    const int tid = threadIdx.x;
    const int wv  = tid >> 6;
    const int ln  = tid & 63;
    const int l15 = ln & 15;
    const int l4  = ln >> 4;
    const int e   = l15 & 7;
    const int wr  = wv >> 1;          // wave row 0..1
    const int wc  = wv & 1;           // wave col 0..1
    const int n0  = blockIdx.x * 128;
    const int m0  = blockIdx.y * 128;

    // staging geometry: thread covers chunks c = kgrp*256 + tid (kgrp 0..3)
    const int rb  = tid >> 3;                        // base row 0..31
    const int csw = ((tid & 7) ^ (rb & 7)) * 8;      // swizzled col (ushorts)
    const int dstw = wv * 512;                       // wave-uniform dest base

    // fragment read offsets (swizzled, unpadded 64-ushort rows)
    const int af0 = (wr * 64 + l15) * 64 + ((l4 ^ e) * 8);
    const int bf0 = (wc * 64 + l15) * 64 + ((l4 ^ e) * 8);

    ffrag acc[4][4];
    #pragma unroll
    for (int i = 0; i < 4; i++)
        #pragma unroll
        for (int j = 0; j < 4; j++) acc[i][j] = (ffrag){0.f, 0.f, 0.f, 0.f};

    // issue step-0 staging
    #pragma unroll
    for (int kg = 0; kg < 4; kg++) {
        const int row = kg * 32 + rb;
        dma16(&xb[(size_t)(m0 + row) * CH + csw], As + kg * 2048 + dstw);
        dma16(&Wt[(size_t)(n0 + row) * CH + csw], Bs + kg * 2048 + dstw);
    }

    for (int s = 0; s < 4; s++) {
        __syncthreads();   // drains DMA for step s (implicit vmcnt(0))
        #pragma unroll
        for (int kk = 0; kk < 2; kk++) {   // two K=32 chunks
            const int x32 = kk * 32;       // XOR 32 toggles chunk bit 2
            bfrag a[4], b[4];
            #pragma unroll
            for (int i = 0; i < 4; i++)
                a[i] = *(const bfrag*)&As[(af0 ^ x32) + i * 1024];
            #pragma unroll
            for (int j = 0; j < 4; j++)
                b[j] = *(const bfrag*)&Bs[(bf0 ^ x32) + j * 1024];
            #pragma unroll
            for (int i = 0; i < 4; i++)
                #pragma unroll
                for (int j = 0; j < 4; j++)
                    acc[i][j] = __builtin_amdgcn_mfma_f32_16x16x32_bf16(a[i], b[j], acc[i][j], 0, 0, 0);
        }
        if (s < 3) {
            __syncthreads();   // all reads of buffer done
            const int k0 = (s + 1) * 64;
            #pragma unroll
            for (int kg = 0; kg < 4; kg++) {
                const int row = kg * 32 + rb;
                dma16(&xb[(size_t)(m0 + row) * CH + k0 + csw], As + kg * 2048 + dstw);
                dma16(&Wt[(size_t)(n0 + row) * CH + k0 + csw], Bs + kg * 2048 + dstw);
            }
        }
    }
    __syncthreads();   // staging done; smem reusable as T

    const int mat = n0 >> 8;                 // block-uniform: 0=Q 1=K 2=V
    const int bb  = m0 >> 11;                // block-uniform
    const int t0  = m0 & (SEQ - 1);
    ushort_t (*T)[136] = (ushort_t(*)[136])smem;

    if (mat < 2) {
        // Q/K: transpose to T[t_local][n_local], then coalesced [T,D] stores.
        const float sc = (mat == 0) ? QSCALE : 1.0f;
        #pragma unroll
        for (int j = 0; j < 4; j++) {
            const int n_local = wc * 64 + j * 16 + l15;
            const float bj = bias[n0 + n_local];
            #pragma unroll
            for (int i = 0; i < 4; i++) {
                const int m_base = wr * 64 + i * 16 + l4 * 4;
                #pragma unroll
                for (int r = 0; r < 4; r++)
                    T[m_base + r][n_local] = f2bf((acc[i][j][r] + bj) * sc);
            }
        }
        __syncthreads();
        ushort_t* dst = (mat == 0) ? Qb : Kb;
        #pragma unroll
        for (int rr = 0; rr < 8; rr++) {
            const int fid = tid + rr * 256;
            const int row = fid >> 4;            // t_local 0..127
            const int c8  = (fid & 15) * 8;      // n_local chunk
            const int n_glob = n0 + c8;
            const int h = (n_glob >> 6) & 3;
            const int d = n_glob & 63;
            *(uint4*)&dst[((size_t)((bb * NH + h) * SEQ) + t0 + row) * HD + d] =
                *(const uint4*)&T[row][c8];
        }
    } else {
        // V: transpose to T[n_local][m_local], then coalesced [D,T] stores.
        #pragma unroll
        for (int j = 0; j < 4; j++) {
            const int n_local = wc * 64 + j * 16 + l15;
            const float bj = bias[n0 + n_local];
            #pragma unroll
            for (int i = 0; i < 4; i++) {
                const int m_base = wr * 64 + i * 16 + l4 * 4;
                ushort4 pk;
                pk.x = f2bf(acc[i][j][0] + bj);
                pk.y = f2bf(acc[i][j][1] + bj);
                pk.z = f2bf(acc[i][j][2] + bj);
                pk.w = f2bf(acc[i][j][3] + bj);
                *(ushort4*)&T[n_local][m_base] = pk;
            }
        }
        __syncthreads();
        #pragma unroll
        for (int rr = 0; rr < 8; rr++) {
            const int fid = tid + rr * 256;
            const int row = fid >> 4;            // n_local 0..127
            const int c8  = (fid & 15) * 8;      // m_local chunk
            const int n_glob = n0 + row;
            const int h = (n_glob >> 6) & 3;
            const int d = n_glob & 63;
            *(uint4*)&Vtb[(size_t)((bb * NH + h) * HD + d) * SEQ + t0 + c8] =
                *(const uint4*)&T[row][c8];
        }
    }
}

// ---------------------------------------------------------------------------
// MFMA flash attention (causal), S^T form, exp2 softmax — round-6 structure
// (best measured) with staging upgraded to async global_load_lds DMA:
//  - BQ=64, double-buffered K/V in LDS, ONE barrier per K-tile iteration
//  - DMA for tile kt+1 issued right after the barrier; drained by the next
//    barrier's implicit vmcnt(0) (a full compute phase to land)
//  - unpadded 64-ushort rows + source-side XOR swizzle (conflict-free image
//    identical to round 6's measured 1.08M-conflict layout)
//  - LDS 40 KB -> 4 blocks/CU; Q frags direct from global; shfl broadcasts
// ---------------------------------------------------------------------------
__global__ __launch_bounds__(256, 4) void attn_mfma_kernel(
    const ushort_t* __restrict__ Qb, const ushort_t* __restrict__ Kb,
    const ushort_t* __restrict__ Vtb, ushort_t* __restrict__ out) {
    __shared__ ushort_t Ps[64 * 64];       // P tiles (wave-private 16-row bands)
    __shared__ ushort_t KV[4 * 64 * 64];   // K0 | K1 | V0 | V1 (8 KB each)

    const int tid = threadIdx.x;
    const int wv  = tid >> 6;
    const int ln  = tid & 63;
    const int l15 = ln & 15;
    const int l4  = ln >> 4;
    const int e   = l15 & 7;

    const int L  = blockIdx.x;
    const int g  = L & 255;
    const int s4 = L >> 8;               // dispatch wave 0..3
    const int v  = g >> 5;               // 0..7
    // longest-first; per-CU slot set {31-v, 16+v, 15-v, v} sums to 66 iters
    const int qb = (s4 == 0) ? (31 - v) : (s4 == 1) ? (16 + v) : (s4 == 2) ? (15 - v) : v;
    const int bh = g & 31;
    const int b  = bh >> 2;
    const int h  = bh & 3;

    // ---- Q fragments straight from global (B-operand: B[n=q][k]) ----
    const ushort_t* Qp = Qb + ((size_t)(bh * SEQ + qb * 64 + wv * 16 + l15)) * HD + l4 * 8;
    const bfrag bq0 = *(const bfrag*)Qp;
    const bfrag bq1 = *(const bfrag*)(Qp + 32);

    // ---- staging geometry (DMA: source swizzled, dest wave-uniform) ----
    const ushort_t* Kbase = Kb  + (size_t)bh * SEQ * HD;
    const ushort_t* Vbase = Vtb + (size_t)bh * HD * SEQ;
    const int rb   = tid >> 3;                       // row 0..31 (second: +32)
    const int csw  = ((tid & 7) ^ (rb & 7)) * 8;     // swizzled col (ushorts)
    const int koff0 = rb * 64 + csw;                 // K source offsets
    const int koff1 = (rb + 32) * 64 + csw;
    const int voff0 = rb * SEQ + csw;                // V source offsets
    const int voff1 = (rb + 32) * SEQ + csw;
    const int dstw  = wv * 512;                      // wave-uniform dest base

    // ---- fragment read offsets (swizzled) ----
    const int kf0 = l15 * 64 + ((l4 ^ e) * 8);   // + n*1024 ; ^32 for chunk 1
    const int pf0 = (wv * 16 + l15) * 64 + ((l4 ^ e) * 8);
    const int pp  = e >> 1;
    const int pwb = (wv * 16 + l15) * 64 + (((l4 >> 1) ^ (e & 1)) * 8) + (l4 & 1) * 4;

    // ---- prologue: issue DMA for tile 0 -> buf0 ----
    dma16(&Kbase[koff0], KV + dstw);
    dma16(&Kbase[koff1], KV + 2048 + dstw);
    dma16(&Vbase[voff0], KV + 8192 + dstw);
    dma16(&Vbase[voff1], KV + 8192 + 2048 + dstw);

    ffrag o[4];
    #pragma unroll
    for (int n = 0; n < 4; n++) o[n] = (ffrag){0.f, 0.f, 0.f, 0.f};
    float m_q = -INFINITY;
    float l_q = 0.f;
    const int qg_l = qb * 64 + wv * 16 + l15;

    for (int kt = 0; kt <= qb; kt++) {
        __syncthreads();   // drains DMA for tile kt; protects buffer reuse

        if (kt < qb) {     // issue DMA for tile kt+1 into the other buffer
            const int nb = ((kt + 1) & 1) * 4096;
            const ushort_t* Kp = Kbase + (size_t)(kt + 1) * 4096;
            const ushort_t* Vp = Vbase + (kt + 1) * 64;
            dma16(&Kp[koff0], KV + nb + dstw);
            dma16(&Kp[koff1], KV + nb + 2048 + dstw);
            dma16(&Vp[voff0], KV + 8192 + nb + dstw);
            dma16(&Vp[voff1], KV + 8192 + nb + 2048 + dstw);
        }

        const ushort_t* Kbuf = KV + (kt & 1) * 4096;
        const ushort_t* Vbuf = KV + 8192 + (kt & 1) * 4096;

        // ---- S^T = K Q^T : s[n][r] = S[q=l15][k = n*16 + l4*4 + r] ----
        ffrag s[4];
        #pragma unroll
        for (int n = 0; n < 4; n++) {
            const bfrag ak0 = *(const bfrag*)&Kbuf[n * 1024 + kf0];
            const bfrag ak1 = *(const bfrag*)&Kbuf[n * 1024 + (kf0 ^ 32)];
            ffrag z = (ffrag){0.f, 0.f, 0.f, 0.f};
            z = __builtin_amdgcn_mfma_f32_16x16x32_bf16(ak0, bq0, z, 0, 0, 0);
            z = __builtin_amdgcn_mfma_f32_16x16x32_bf16(ak1, bq1, z, 0, 0, 0);
            s[n] = z;
        }
        if (kt == qb) {   // causal mask on the diagonal tile
            #pragma unroll
            for (int n = 0; n < 4; n++)
                #pragma unroll
                for (int r = 0; r < 4; r++)
                    if (kt * 64 + n * 16 + l4 * 4 + r > qg_l) s[n][r] = -INFINITY;
        }

        // ---- online softmax (exp2 domain) ----
        float mx = s[0][0];
        #pragma unroll
        for (int n = 0; n < 4; n++)
            #pragma unroll
            for (int r = 0; r < 4; r++) mx = fmaxf(mx, s[n][r]);
        mx = fmaxf(mx, __shfl_xor(mx, 16));
        mx = fmaxf(mx, __shfl_xor(mx, 32));
        const float mn = fmaxf(m_q, mx);
        const float alpha = __builtin_amdgcn_exp2f(m_q - mn);
        m_q = mn;

        float rs = 0.f;
        #pragma unroll
        for (int n = 0; n < 4; n++)
            #pragma unroll
            for (int r = 0; r < 4; r++) {
                const float p = __builtin_amdgcn_exp2f(s[n][r] - mn);
                s[n][r] = p;
                rs += p;
            }
        rs += __shfl_xor(rs, 16);
        rs += __shfl_xor(rs, 32);
        l_q = l_q * alpha + rs;

        // ---- pack P (bf16, A-layout, swizzled, wave-private rows) ----
        #pragma unroll
        for (int n = 0; n < 4; n++) {
            uint2 pk;
            pk.x = pack2(s[n][0], s[n][1]);
            pk.y = pack2(s[n][2], s[n][3]);
            *(uint2*)&Ps[pwb + ((n ^ pp) << 4)] = pk;
        }

        // ---- O *= alpha (row l4*4+r alpha via shuffle) ----
        #pragma unroll
        for (int r = 0; r < 4; r++) {
            const float ar = __shfl(alpha, l4 * 20 + r);
            #pragma unroll
            for (int n = 0; n < 4; n++) o[n][r] *= ar;
        }

        // ---- O += P @ V ----
        const bfrag ap0 = *(const bfrag*)&Ps[pf0];
        const bfrag ap1 = *(const bfrag*)&Ps[pf0 ^ 32];
        #pragma unroll
        for (int n = 0; n < 4; n++) {
            const bfrag bv0 = *(const bfrag*)&Vbuf[n * 1024 + kf0];
            const bfrag bv1 = *(const bfrag*)&Vbuf[n * 1024 + (kf0 ^ 32)];
            o[n] = __builtin_amdgcn_mfma_f32_16x16x32_bf16(ap0, bv0, o[n], 0, 0, 0);
            o[n] = __builtin_amdgcn_mfma_f32_16x16x32_bf16(ap1, bv1, o[n], 0, 0, 0);
        }
    }

    // ---- normalize + store O (bf16, [B,T,C]) ----
    const int tg = qb * 64 + wv * 16 + l4 * 4;
    ushort_t* op = out + (size_t)(b * SEQ) * CH + h * HD;
    #pragma unroll
    for (int r = 0; r < 4; r++) {
        const float lr = __shfl(l_q, l4 * 20 + r);
        const float li = 1.0f / lr;
        #pragma unroll
        for (int n = 0; n < 4; n++)
            op[(size_t)(tg + r) * CH + n * 16 + l15] = f2bf(o[n][r] * li);
    }
}

// ---------------------------------------------------------------------------
// Proj MFMA GEMM: attn_b(16384x256) @ WprojT^T + bproj -> fp32 out.
// 128x64 tile (4 waves: 2x2, each 64x32), grid 512 -> 2 blocks/CU.
// (round-6 version, part of the best measured config)
// ---------------------------------------------------------------------------
#define GLS 72

__global__ __launch_bounds__(256) void proj_mfma_kernel(
    const ushort_t* __restrict__ Ab, const ushort_t* __restrict__ Wt,
    const float* __restrict__ bias, float* __restrict__ O) {
    __shared__ ushort_t smem[(128 + 64) * GLS];
    ushort_t* As = smem;
    ushort_t* Bs = smem + 128 * GLS;

    const int tid = threadIdx.x;
    const int wv  = tid >> 6;
    const int ln  = tid & 63;
    const int l15 = ln & 15;
    const int l4  = ln >> 4;
    const int wr  = wv >> 1;          // 0..1 -> 64-row band
    const int wc  = wv & 1;           // 0..1 -> 32-col band
    const int n0  = blockIdx.x * 64;
    const int m0  = blockIdx.y * 128;

    ffrag acc[4][2];
    #pragma unroll
    for (int i = 0; i < 4; i++)
        #pragma unroll
        for (int j = 0; j < 2; j++) acc[i][j] = (ffrag){0.f, 0.f, 0.f, 0.f};

    for (int k0 = 0; k0 < CH; k0 += 64) {
        #pragma unroll
        for (int r = 0; r < 4; r++) {   // A: 128x64 = 1024 chunks
            const int fid = tid + r * 256;
            const int row = fid >> 3, c8 = (fid & 7) * 8;
            *(uint4*)&As[row * GLS + c8] = *(const uint4*)&Ab[(size_t)(m0 + row) * CH + k0 + c8];
        }
        #pragma unroll
        for (int r = 0; r < 2; r++) {   // B: 64x64 = 512 chunks
            const int fid = tid + r * 256;
            const int row = fid >> 3, c8 = (fid & 7) * 8;
            *(uint4*)&Bs[row * GLS + c8] = *(const uint4*)&Wt[(n0 + row) * CH + k0 + c8];
        }
        __syncthreads();
        #pragma unroll
        for (int kk = 0; kk < 64; kk += 32) {
            bfrag a[4], b[2];
            #pragma unroll
            for (int i = 0; i < 4; i++)
                a[i] = *(const bfrag*)&As[(wr * 64 + i * 16 + l15) * GLS + kk + l4 * 8];
            #pragma unroll
            for (int j = 0; j < 2; j++)
                b[j] = *(const bfrag*)&Bs[(wc * 32 + j * 16 + l15) * GLS + kk + l4 * 8];
            #pragma unroll
            for (int i = 0; i < 4; i++)
                #pragma unroll
                for (int j = 0; j < 2; j++)
                    acc[i][j] = __builtin_amdgcn_mfma_f32_16x16x32_bf16(a[i], b[j], acc[i][j], 0, 0, 0);
        }
        __syncthreads();
    }

    #pragma unroll
    for (int j = 0; j < 2; j++) {
        const int n = n0 + wc * 32 + j * 16 + l15;
        const float bj = bias[n];
        #pragma unroll
        for (int i = 0; i < 4; i++) {
            const int m = m0 + wr * 64 + i * 16 + l4 * 4;
            #pragma unroll
            for (int r = 0; r < 4; r++)
                O[(size_t)(m + r) * CH + n] = acc[i][j][r] + bj;
        }
    }
}

extern "C" void kernel_launch(void* const* d_in, const int* in_sizes, int n_in,
                              void* d_out, int out_size, void* d_ws, size_t ws_size,
                              hipStream_t stream) {
    const float* x     = (const float*)d_in[0];
    const float* Wqkv  = (const float*)d_in[1];
    const float* bqkv  = (const float*)d_in[2];
    const float* Wproj = (const float*)d_in[3];
    const float* bproj = (const float*)d_in[4];
    float* out = (float*)d_out;

    const size_t BHTD = (size_t)BATCH * NH * SEQ * HD;   // 4,194,304
    ushort_t* xb     = (ushort_t*)d_ws;
    ushort_t* WqkvT  = xb + BHTD;
    ushort_t* WprojT = WqkvT + (size_t)3 * CH * CH;
    ushort_t* Qb     = WprojT + (size_t)CH * CH;
    ushort_t* Kb     = Qb + BHTD;
    ushort_t* Vtb    = Kb + BHTD;
    ushort_t* attn_b = Vtb + BHTD;

    const int M = BATCH * SEQ;   // 16384

    {
        const int total = XN + WQN + WPN;
        prep_kernel<<<(total + 255) / 256, 256, 0, stream>>>(x, Wqkv, Wproj, xb, WqkvT, WprojT);
    }
    {
        dim3 grid((3 * CH) / 128, M / 128);
        qkv_mfma_kernel<<<grid, 256, 0, stream>>>(xb, WqkvT, bqkv, Qb, Kb, Vtb);
    }
    {
        attn_mfma_kernel<<<dim3(NQB * BATCH * NH), 256, 0, stream>>>(Qb, Kb, Vtb, attn_b);
    }
    {
        dim3 grid(CH / 64, M / 128);
        proj_mfma_kernel<<<grid, 256, 0, stream>>>(attn_b, WprojT, bproj, out);
    }
}

// Round 11
// 142.973 us; speedup vs baseline: 1.4487x; 1.0660x over previous
//
#include <hip/hip_runtime.h>
#include <hip/hip_bf16.h>
#include <math.h>

#define BATCH 8
#define SEQ   2048
#define CH    256
#define NH    4
#define HD    64
#define NQB   (SEQ / 64)      // 32 query tiles of 64
// Q pre-scale: 64^-0.5 * log2(e)  (softmax runs in exp2 domain)
#define QSCALE 0.18033688011112042f

typedef short  bfrag __attribute__((ext_vector_type(8)));  // 8 bf16 (4 VGPRs)
typedef float  ffrag __attribute__((ext_vector_type(4)));  // 4 fp32 acc
typedef unsigned short ushort_t;

__device__ __forceinline__ unsigned short f2bf(float f) {
    union { float f; unsigned int u; } v; v.f = f;
    unsigned int r = v.u + 0x7FFF + ((v.u >> 16) & 1);   // RNE
    return (unsigned short)(r >> 16);
}
__device__ __forceinline__ unsigned int pack2(float a, float b) {
    const __hip_bfloat162 p = __float22bfloat162_rn(make_float2(a, b));
    return *(const unsigned int*)&p;
}

// ---------------------------------------------------------------------------
// Prep (weights only): Wqkv, Wproj -> transposed bf16 (W^T[n][k]).
// ---------------------------------------------------------------------------
#define WQN (CH * 3 * CH)            // 196608
#define WPN (CH * CH)                // 65536

__global__ __launch_bounds__(256) void prep_kernel(
    const float* __restrict__ Wqkv, const float* __restrict__ Wproj,
    ushort_t* __restrict__ WqkvT, ushort_t* __restrict__ WprojT) {
    const int fid = blockIdx.x * 256 + threadIdx.x;
    if (fid < WQN) {
        const int n = fid >> 8, k = fid & 255;
        WqkvT[n * CH + k] = f2bf(Wqkv[k * (3 * CH) + n]);
    } else if (fid < WQN + WPN) {
        const int i = fid - WQN;
        const int n = i >> 8, k = i & 255;
        WprojT[n * CH + k] = f2bf(Wproj[k * CH + n]);
    }
}

// ---------------------------------------------------------------------------
// QKV MFMA GEMM (round-6 version, best measured): x fp32 @ WqkvT^T + bqkv ->
// bf16 Q(*QSCALE),K [BH,T,D], V^T [BH,D,T]. 128x128 tile, 4 waves each 64x64,
// BK=64; x converted fp32->bf16 during LDS staging.
// ---------------------------------------------------------------------------
#define GLS 72   // LDS row stride in ushorts (144 B, 16B-aligned)

__global__ __launch_bounds__(256) void qkv_mfma_kernel(
    const float* __restrict__ x, const ushort_t* __restrict__ Wt,
    const float* __restrict__ bias,
    ushort_t* __restrict__ Qb, ushort_t* __restrict__ Kb,
    ushort_t* __restrict__ Vtb) {
    __shared__ ushort_t smem[2 * 128 * GLS];   // As | Bs; reused as T[128][136]
    ushort_t* As = smem;
    ushort_t* Bs = smem + 128 * GLS;

    const int tid = threadIdx.x;
    const int wv  = tid >> 6;
    const int ln  = tid & 63;
    const int l15 = ln & 15;
    const int l4  = ln >> 4;
    const int wr  = wv >> 1;          // wave row 0..1
    const int wc  = wv & 1;           // wave col 0..1
    const int n0  = blockIdx.x * 128;
    const int m0  = blockIdx.y * 128;

    ffrag acc[4][4];
    #pragma unroll
    for (int i = 0; i < 4; i++)
        #pragma unroll
        for (int j = 0; j < 4; j++) acc[i][j] = (ffrag){0.f, 0.f, 0.f, 0.f};

    for (int k0 = 0; k0 < CH; k0 += 64) {
        #pragma unroll
        for (int r = 0; r < 4; r++) {
            const int fid = tid + r * 256;
            const int row = fid >> 3, c8 = (fid & 7) * 8;
            // A: read 8 fp32 of x, convert to bf16 on the fly
            const float* xp = &x[(size_t)(m0 + row) * CH + k0 + c8];
            const float4 va = *(const float4*)xp;
            const float4 vb = *(const float4*)(xp + 4);
            uint4 pk;
            pk.x = pack2(va.x, va.y); pk.y = pack2(va.z, va.w);
            pk.z = pack2(vb.x, vb.y); pk.w = pack2(vb.z, vb.w);
            *(uint4*)&As[row * GLS + c8] = pk;
            *(uint4*)&Bs[row * GLS + c8] = *(const uint4*)&Wt[(n0 + row) * CH + k0 + c8];
        }
        __syncthreads();
        #pragma unroll
        for (int kk = 0; kk < 64; kk += 32) {
            bfrag a[4], b[4];
            #pragma unroll
            for (int i = 0; i < 4; i++)
                a[i] = *(const bfrag*)&As[(wr * 64 + i * 16 + l15) * GLS + kk + l4 * 8];
            #pragma unroll
            for (int j = 0; j < 4; j++)
                b[j] = *(const bfrag*)&Bs[(wc * 64 + j * 16 + l15) * GLS + kk + l4 * 8];
            #pragma unroll
            for (int i = 0; i < 4; i++)
                #pragma unroll
                for (int j = 0; j < 4; j++)
                    acc[i][j] = __builtin_amdgcn_mfma_f32_16x16x32_bf16(a[i], b[j], acc[i][j], 0, 0, 0);
        }
        __syncthreads();
    }

    const int mat = n0 >> 8;                 // block-uniform: 0=Q 1=K 2=V
    const int b   = m0 >> 11;                // block-uniform
    const int t0  = m0 & (SEQ - 1);
    ushort_t (*T)[136] = (ushort_t(*)[136])smem;

    if (mat < 2) {
        // Q/K: transpose to T[t_local][n_local], then coalesced [T,D] stores.
        const float sc = (mat == 0) ? QSCALE : 1.0f;
        #pragma unroll
        for (int j = 0; j < 4; j++) {
            const int n_local = wc * 64 + j * 16 + l15;
            const float bj = bias[n0 + n_local];
            #pragma unroll
            for (int i = 0; i < 4; i++) {
                const int m_base = wr * 64 + i * 16 + l4 * 4;
                #pragma unroll
                for (int r = 0; r < 4; r++)
                    T[m_base + r][n_local] = f2bf((acc[i][j][r] + bj) * sc);
            }
        }
        __syncthreads();
        ushort_t* dst = (mat == 0) ? Qb : Kb;
        #pragma unroll
        for (int rr = 0; rr < 8; rr++) {
            const int fid = tid + rr * 256;
            const int row = fid >> 4;            // t_local 0..127
            const int c8  = (fid & 15) * 8;      // n_local chunk
            const int n_glob = n0 + c8;
            const int h = (n_glob >> 6) & 3;
            const int d = n_glob & 63;
            *(uint4*)&dst[((size_t)((b * NH + h) * SEQ) + t0 + row) * HD + d] =
                *(const uint4*)&T[row][c8];
        }
    } else {
        // V: transpose to T[n_local][m_local], then coalesced [D,T] stores.
        #pragma unroll
        for (int j = 0; j < 4; j++) {
            const int n_local = wc * 64 + j * 16 + l15;
            const float bj = bias[n0 + n_local];
            #pragma unroll
            for (int i = 0; i < 4; i++) {
                const int m_base = wr * 64 + i * 16 + l4 * 4;
                ushort4 pk;
                pk.x = f2bf(acc[i][j][0] + bj);
                pk.y = f2bf(acc[i][j][1] + bj);
                pk.z = f2bf(acc[i][j][2] + bj);
                pk.w = f2bf(acc[i][j][3] + bj);
                *(ushort4*)&T[n_local][m_base] = pk;
            }
        }
        __syncthreads();
        #pragma unroll
        for (int rr = 0; rr < 8; rr++) {
            const int fid = tid + rr * 256;
            const int row = fid >> 4;            // n_local 0..127
            const int c8  = (fid & 15) * 8;      // m_local chunk
            const int n_glob = n0 + row;
            const int h = (n_glob >> 6) & 3;
            const int d = n_glob & 63;
            *(uint4*)&Vtb[(size_t)((b * NH + h) * HD + d) * SEQ + t0 + c8] =
                *(const uint4*)&T[row][c8];
        }
    }
}

// ---------------------------------------------------------------------------
// MFMA flash attention (causal), S^T form, exp2 softmax — round-6 structure
// (best measured) + PV computed TRANSPOSED: O^T = V^T * P^T.
// Same Ps/Vts fragment reads (identical addresses) with mfma args swapped;
// the C-layout flip puts q on lane&15 for the O accumulator, so alpha / 1/l
// are applied IN-LANE (removes all 5 broadcast shuffles per iteration) and
// the epilogue becomes 4x contiguous ushort4 stores per lane.
// ---------------------------------------------------------------------------
__global__ __launch_bounds__(256, 4) void attn_mfma_kernel(
    const ushort_t* __restrict__ Qb, const ushort_t* __restrict__ Kb,
    const ushort_t* __restrict__ Vtb, ushort_t* __restrict__ out) {
    __shared__ ushort_t Ps[64 * 64];       // P tiles (wave-private 16-row bands)
    __shared__ ushort_t KV[4 * 64 * 64];   // K0 | K1 | V0 | V1 (8 KB each)

    const int tid = threadIdx.x;
    const int wv  = tid >> 6;
    const int ln  = tid & 63;
    const int l15 = ln & 15;
    const int l4  = ln >> 4;
    const int e   = l15 & 7;

    const int L  = blockIdx.x;
    const int g  = L & 255;
    const int s4 = L >> 8;               // dispatch wave 0..3
    const int v  = g >> 5;               // 0..7
    // longest-first; per-CU slot set {31-v, 16+v, 15-v, v} sums to 66 iters
    const int qb = (s4 == 0) ? (31 - v) : (s4 == 1) ? (16 + v) : (s4 == 2) ? (15 - v) : v;
    const int bh = g & 31;
    const int b  = bh >> 2;
    const int h  = bh & 3;

    // ---- Q fragments straight from global (B-operand: B[n=q][k]) ----
    const ushort_t* Qp = Qb + ((size_t)(bh * SEQ + qb * 64 + wv * 16 + l15)) * HD + l4 * 8;
    const bfrag bq0 = *(const bfrag*)Qp;
    const bfrag bq1 = *(const bfrag*)(Qp + 32);

    // ---- staging geometry ----
    const ushort_t* Kbase = Kb  + (size_t)bh * SEQ * HD;
    const ushort_t* Vbase = Vtb + (size_t)bh * HD * SEQ;
    const int srow  = tid >> 3;            // 0..31
    const int sc    = tid & 7;             // logical 16B-chunk
    const int goffA = srow * 64 + sc * 8;              // K global (ushorts)
    const int voffA = srow * SEQ + sc * 8;             // V global
    const int soffA = srow * 64 + ((sc ^ (srow & 7)) * 8);   // swizzled LDS

    // ---- fragment read offsets (precomputed, swizzled) ----
    const int kf0 = l15 * 64 + ((l4 ^ e) * 8);   // + n*1024 ; ^32 for k-chunk 1
    const int pf0 = (wv * 16 + l15) * 64 + ((l4 ^ e) * 8);
    const int pp  = e >> 1;
    const int pwb = (wv * 16 + l15) * 64 + (((l4 >> 1) ^ (e & 1)) * 8) + (l4 & 1) * 4;

    // ---- prologue: tile 0 -> regs -> LDS buf0 ; tile 1 -> regs ----
    uint4 kK0, kK1, kV0, kV1;
    kK0 = *(const uint4*)&Kbase[goffA];
    kK1 = *(const uint4*)&Kbase[goffA + 32 * 64];
    kV0 = *(const uint4*)&Vbase[voffA];
    kV1 = *(const uint4*)&Vbase[voffA + 32 * SEQ];
    *(uint4*)&KV[soffA]          = kK0;
    *(uint4*)&KV[soffA + 2048]   = kK1;
    *(uint4*)&KV[8192 + soffA]        = kV0;
    *(uint4*)&KV[8192 + soffA + 2048] = kV1;
    if (qb >= 1) {
        kK0 = *(const uint4*)&Kbase[4096 + goffA];
        kK1 = *(const uint4*)&Kbase[4096 + goffA + 32 * 64];
        kV0 = *(const uint4*)&Vbase[64 + voffA];
        kV1 = *(const uint4*)&Vbase[64 + voffA + 32 * SEQ];
    }

    ffrag o[4];   // O^T accumulator: o[n][r] = O^T[d = n*16+l4*4+r][q = l15]
    #pragma unroll
    for (int n = 0; n < 4; n++) o[n] = (ffrag){0.f, 0.f, 0.f, 0.f};
    float m_q = -INFINITY;
    float l_q = 0.f;
    const int qg_l = qb * 64 + wv * 16 + l15;

    for (int kt = 0; kt <= qb; kt++) {
        if (kt > 0) {
            // commit prefetched tile kt into buffer kt&1
            const int kb = (kt & 1) * 4096;
            *(uint4*)&KV[kb + soffA]          = kK0;
            *(uint4*)&KV[kb + soffA + 2048]   = kK1;
            *(uint4*)&KV[8192 + kb + soffA]        = kV0;
            *(uint4*)&KV[8192 + kb + soffA + 2048] = kV1;
            if (kt < qb) {   // issue loads for tile kt+1 (land during compute)
                const ushort_t* Kp  = Kbase + (kt + 1) * 4096;
                const ushort_t* Vtp = Vbase + (kt + 1) * 64;
                kK0 = *(const uint4*)&Kp[goffA];
                kK1 = *(const uint4*)&Kp[goffA + 32 * 64];
                kV0 = *(const uint4*)&Vtp[voffA];
                kV1 = *(const uint4*)&Vtp[voffA + 32 * SEQ];
            }
        }
        __syncthreads();   // the ONLY barrier in the iteration

        const ushort_t* Kbuf = KV + (kt & 1) * 4096;
        const ushort_t* Vbuf = KV + 8192 + (kt & 1) * 4096;

        // ---- S^T = K Q^T : s[n][r] = S[q=l15][k = n*16 + l4*4 + r] ----
        ffrag s[4];
        #pragma unroll
        for (int n = 0; n < 4; n++) {
            const bfrag ak0 = *(const bfrag*)&Kbuf[n * 1024 + kf0];
            const bfrag ak1 = *(const bfrag*)&Kbuf[n * 1024 + (kf0 ^ 32)];
            ffrag z = (ffrag){0.f, 0.f, 0.f, 0.f};
            z = __builtin_amdgcn_mfma_f32_16x16x32_bf16(ak0, bq0, z, 0, 0, 0);
            z = __builtin_amdgcn_mfma_f32_16x16x32_bf16(ak1, bq1, z, 0, 0, 0);
            s[n] = z;
        }
        if (kt == qb) {   // causal mask on the diagonal tile
            #pragma unroll
            for (int n = 0; n < 4; n++)
                #pragma unroll
                for (int r = 0; r < 4; r++)
                    if (kt * 64 + n * 16 + l4 * 4 + r > qg_l) s[n][r] = -INFINITY;
        }

        // ---- online softmax (exp2 domain) ----
        float mx = s[0][0];
        #pragma unroll
        for (int n = 0; n < 4; n++)
            #pragma unroll
            for (int r = 0; r < 4; r++) mx = fmaxf(mx, s[n][r]);
        mx = fmaxf(mx, __shfl_xor(mx, 16));
        mx = fmaxf(mx, __shfl_xor(mx, 32));
        const float mn = fmaxf(m_q, mx);
        const float alpha = __builtin_amdgcn_exp2f(m_q - mn);
        m_q = mn;

        float rs = 0.f;
        #pragma unroll
        for (int n = 0; n < 4; n++)
            #pragma unroll
            for (int r = 0; r < 4; r++) {
                const float p = __builtin_amdgcn_exp2f(s[n][r] - mn);
                s[n][r] = p;
                rs += p;
            }
        rs += __shfl_xor(rs, 16);
        rs += __shfl_xor(rs, 32);
        l_q = l_q * alpha + rs;

        // ---- pack P (bf16, A/B-layout rows q, swizzled, wave-private) ----
        #pragma unroll
        for (int n = 0; n < 4; n++) {
            uint2 pk;
            pk.x = pack2(s[n][0], s[n][1]);
            pk.y = pack2(s[n][2], s[n][3]);
            *(uint2*)&Ps[pwb + ((n ^ pp) << 4)] = pk;
        }

        // ---- O^T *= alpha : accumulator cols are q=l15 -> alpha is IN-LANE --
        #pragma unroll
        for (int n = 0; n < 4; n++)
            #pragma unroll
            for (int r = 0; r < 4; r++) o[n][r] *= alpha;

        // ---- O^T += V^T @ P^T  (same frags as r6, mfma args swapped) ----
        const bfrag ap0 = *(const bfrag*)&Ps[pf0];
        const bfrag ap1 = *(const bfrag*)&Ps[pf0 ^ 32];
        #pragma unroll
        for (int n = 0; n < 4; n++) {
            const bfrag av0 = *(const bfrag*)&Vbuf[n * 1024 + kf0];
            const bfrag av1 = *(const bfrag*)&Vbuf[n * 1024 + (kf0 ^ 32)];
            o[n] = __builtin_amdgcn_mfma_f32_16x16x32_bf16(av0, ap0, o[n], 0, 0, 0);
            o[n] = __builtin_amdgcn_mfma_f32_16x16x32_bf16(av1, ap1, o[n], 0, 0, 0);
        }
    }

    // ---- normalize + store O (bf16, [B,T,C]): in-lane 1/l, vector stores ----
    const float li = 1.0f / l_q;
    const int tq = qb * 64 + wv * 16 + l15;        // this lane's q row
    ushort_t* op = out + (size_t)(b * SEQ + tq) * CH + h * HD;
    #pragma unroll
    for (int n = 0; n < 4; n++) {
        ushort4 pk;
        pk.x = f2bf(o[n][0] * li);
        pk.y = f2bf(o[n][1] * li);
        pk.z = f2bf(o[n][2] * li);
        pk.w = f2bf(o[n][3] * li);
        *(ushort4*)&op[n * 16 + l4 * 4] = pk;      // d = n*16 + l4*4 .. +3
    }
}

// ---------------------------------------------------------------------------
// Proj MFMA GEMM (round-6 version): attn_b @ WprojT^T + bproj -> fp32 out.
// 128x64 tile (4 waves: 2x2, each 64x32), grid 512 -> 2 blocks/CU.
// ---------------------------------------------------------------------------
__global__ __launch_bounds__(256) void proj_mfma_kernel(
    const ushort_t* __restrict__ Ab, const ushort_t* __restrict__ Wt,
    const float* __restrict__ bias, float* __restrict__ O) {
    __shared__ ushort_t smem[(128 + 64) * GLS];
    ushort_t* As = smem;
    ushort_t* Bs = smem + 128 * GLS;

    const int tid = threadIdx.x;
    const int wv  = tid >> 6;
    const int ln  = tid & 63;
    const int l15 = ln & 15;
    const int l4  = ln >> 4;
    const int wr  = wv >> 1;          // 0..1 -> 64-row band
    const int wc  = wv & 1;           // 0..1 -> 32-col band
    const int n0  = blockIdx.x * 64;
    const int m0  = blockIdx.y * 128;

    ffrag acc[4][2];
    #pragma unroll
    for (int i = 0; i < 4; i++)
        #pragma unroll
        for (int j = 0; j < 2; j++) acc[i][j] = (ffrag){0.f, 0.f, 0.f, 0.f};

    for (int k0 = 0; k0 < CH; k0 += 64) {
        #pragma unroll
        for (int r = 0; r < 4; r++) {   // A: 128x64 = 1024 chunks
            const int fid = tid + r * 256;
            const int row = fid >> 3, c8 = (fid & 7) * 8;
            *(uint4*)&As[row * GLS + c8] = *(const uint4*)&Ab[(size_t)(m0 + row) * CH + k0 + c8];
        }
        #pragma unroll
        for (int r = 0; r < 2; r++) {   // B: 64x64 = 512 chunks
            const int fid = tid + r * 256;
            const int row = fid >> 3, c8 = (fid & 7) * 8;
            *(uint4*)&Bs[row * GLS + c8] = *(const uint4*)&Wt[(n0 + row) * CH + k0 + c8];
        }
        __syncthreads();
        #pragma unroll
        for (int kk = 0; kk < 64; kk += 32) {
            bfrag a[4], b[2];
            #pragma unroll
            for (int i = 0; i < 4; i++)
                a[i] = *(const bfrag*)&As[(wr * 64 + i * 16 + l15) * GLS + kk + l4 * 8];
            #pragma unroll
            for (int j = 0; j < 2; j++)
                b[j] = *(const bfrag*)&Bs[(wc * 32 + j * 16 + l15) * GLS + kk + l4 * 8];
            #pragma unroll
            for (int i = 0; i < 4; i++)
                #pragma unroll
                for (int j = 0; j < 2; j++)
                    acc[i][j] = __builtin_amdgcn_mfma_f32_16x16x32_bf16(a[i], b[j], acc[i][j], 0, 0, 0);
        }
        __syncthreads();
    }

    #pragma unroll
    for (int j = 0; j < 2; j++) {
        const int n = n0 + wc * 32 + j * 16 + l15;
        const float bj = bias[n];
        #pragma unroll
        for (int i = 0; i < 4; i++) {
            const int m = m0 + wr * 64 + i * 16 + l4 * 4;
            #pragma unroll
            for (int r = 0; r < 4; r++)
                O[(size_t)(m + r) * CH + n] = acc[i][j][r] + bj;
        }
    }
}

extern "C" void kernel_launch(void* const* d_in, const int* in_sizes, int n_in,
                              void* d_out, int out_size, void* d_ws, size_t ws_size,
                              hipStream_t stream) {
    const float* x     = (const float*)d_in[0];
    const float* Wqkv  = (const float*)d_in[1];
    const float* bqkv  = (const float*)d_in[2];
    const float* Wproj = (const float*)d_in[3];
    const float* bproj = (const float*)d_in[4];
    float* out = (float*)d_out;

    const size_t BHTD = (size_t)BATCH * NH * SEQ * HD;   // 4,194,304
    ushort_t* WqkvT  = (ushort_t*)d_ws;
    ushort_t* WprojT = WqkvT + (size_t)3 * CH * CH;
    ushort_t* Qb     = WprojT + (size_t)CH * CH;
    ushort_t* Kb     = Qb + BHTD;
    ushort_t* Vtb    = Kb + BHTD;
    ushort_t* attn_b = Vtb + BHTD;

    const int M = BATCH * SEQ;   // 16384

    {
        const int total = WQN + WPN;
        prep_kernel<<<(total + 255) / 256, 256, 0, stream>>>(Wqkv, Wproj, WqkvT, WprojT);
    }
    {
        dim3 grid((3 * CH) / 128, M / 128);
        qkv_mfma_kernel<<<grid, 256, 0, stream>>>(x, WqkvT, bqkv, Qb, Kb, Vtb);
    }
    {
        attn_mfma_kernel<<<dim3(NQB * BATCH * NH), 256, 0, stream>>>(Qb, Kb, Vtb, attn_b);
    }
    {
        dim3 grid(CH / 64, M / 128);
        proj_mfma_kernel<<<grid, 256, 0, stream>>>(attn_b, WprojT, bproj, out);
    }
}